// Round 1
// baseline (109.871 us; speedup 1.0000x reference)
//
#include <hip/hip_runtime.h>

// Vanilla RNN, B=4096 S=512 I=1 H=16 O=1.
// Layout: lane = (batch, h-row). 16 consecutive lanes = one batch element.
// 65536 threads = 1024 waves = 1 wave/SIMD device-wide (parallelism cap).
// Cross-lane h broadcast via DPP row_ror (VALU pipe, no LDS contention).
// Weights pre-permuted per-lane using the HW's own rotation of the lane
// index -> correct regardless of DPP rotate direction.
// tanh(z) = 1 - 2/(2^(S2LE*z)+1) with S2LE = 2*log2(e) folded into weights.

#define S2LE 2.8853900817779268f  // 2*log2(e)

#define ROTI(v, N) __builtin_amdgcn_mov_dpp((v), 0x120 + (N), 0xF, 0xF, 0)
#define ROTF(v, N) __int_as_float(__builtin_amdgcn_mov_dpp(__float_as_int(v), 0x120 + (N), 0xF, 0xF, 0))

__global__ __launch_bounds__(64) void rnn_kernel(
    const float* __restrict__ x,
    const float* __restrict__ W_ih,
    const float* __restrict__ W_hh,
    const float* __restrict__ b_ih,
    const float* __restrict__ b_hh,
    const float* __restrict__ W_fc,
    const float* __restrict__ b_fc,
    float* __restrict__ out)
{
    const int li = (int)(threadIdx.x & 15u);
    const int b  = (int)((blockIdx.x * 64u + threadIdx.x) >> 4);

    const float* __restrict__ row = W_hh + li * 16;

    // Self-calibrating weight permutation: w[N] holds W_hh[i][sigma_N(i)]
    // where sigma_N is whatever permutation row_ror:N actually applies.
    float w[16];
    w[0] = row[li] * S2LE;
#define LW(N) { int s_ = ROTI(li, N); w[N] = row[s_] * S2LE; }
    LW(1) LW(2) LW(3) LW(4) LW(5) LW(6) LW(7) LW(8)
    LW(9) LW(10) LW(11) LW(12) LW(13) LW(14) LW(15)
#undef LW

    const float wih  = W_ih[li] * S2LE;
    const float bias = (b_ih[li] + b_hh[li]) * S2LE;
    const float wfc  = W_fc[li];
    const float bfc  = b_fc[0];

    const float4* __restrict__ xv = (const float4*)(x + (size_t)b * 512);

    float h = 0.0f;
    float4 xc = xv[0];

    // One recurrent step. y accumulates the (pre-scaled) preactivation in
    // 4 independent FMA chains for ILP; DPP rotations feed the cross-lane
    // h values straight into the FMAs (foldable to v_fmac_f32_dpp).
#define STEP(XV) do { \
    float y0 = fmaf((XV), wih, bias); \
    y0 = fmaf(w[0], h, y0); \
    y0 = fmaf(w[1], ROTF(h, 1), y0); \
    y0 = fmaf(w[2], ROTF(h, 2), y0); \
    y0 = fmaf(w[3], ROTF(h, 3), y0); \
    float y1 = w[4] * ROTF(h, 4); \
    y1 = fmaf(w[5], ROTF(h, 5), y1); \
    y1 = fmaf(w[6], ROTF(h, 6), y1); \
    y1 = fmaf(w[7], ROTF(h, 7), y1); \
    float y2 = w[8] * ROTF(h, 8); \
    y2 = fmaf(w[9], ROTF(h, 9), y2); \
    y2 = fmaf(w[10], ROTF(h, 10), y2); \
    y2 = fmaf(w[11], ROTF(h, 11), y2); \
    float y3 = w[12] * ROTF(h, 12); \
    y3 = fmaf(w[13], ROTF(h, 13), y3); \
    y3 = fmaf(w[14], ROTF(h, 14), y3); \
    y3 = fmaf(w[15], ROTF(h, 15), y3); \
    y0 = (y0 + y1) + (y2 + y3); \
    float e_ = __builtin_amdgcn_exp2f(y0); \
    float r_ = __builtin_amdgcn_rcpf(e_ + 1.0f); \
    h = fmaf(-2.0f, r_, 1.0f); \
} while (0)

#pragma unroll 1
    for (int c = 0; c < 128; ++c) {
        float4 xn = xv[(c + 1) & 127];  // prefetch next chunk (wraps safely)
        STEP(xc.x);
        STEP(xc.y);
        STEP(xc.z);
        STEP(xc.w);
        xc = xn;
    }
#undef STEP

    // out[b] = sum_i h[i]*W_fc[0][i] + b_fc. Rotation-based 16-lane
    // reduction (direction-agnostic: offsets {8,4,2,1} cover all 16).
    float p = h * wfc;
    p += ROTF(p, 8);
    p += ROTF(p, 4);
    p += ROTF(p, 2);
    p += ROTF(p, 1);
    if (li == 0) out[b] = p + bfc;
}

extern "C" void kernel_launch(void* const* d_in, const int* in_sizes, int n_in,
                              void* d_out, int out_size, void* d_ws, size_t ws_size,
                              hipStream_t stream) {
    const float* x    = (const float*)d_in[0];
    const float* W_ih = (const float*)d_in[1];
    const float* W_hh = (const float*)d_in[2];
    const float* b_ih = (const float*)d_in[3];
    const float* b_hh = (const float*)d_in[4];
    const float* W_fc = (const float*)d_in[5];
    const float* b_fc = (const float*)d_in[6];
    float* out = (float*)d_out;

    rnn_kernel<<<1024, 64, 0, stream>>>(x, W_ih, W_hh, b_ih, b_hh, W_fc, b_fc, out);
}

// Round 2
// 106.610 us; speedup vs baseline: 1.0306x; 1.0306x over previous
//
#include <hip/hip_runtime.h>

// Vanilla RNN, B=4096 S=512 I=1 H=16 O=1.
// Lane = (batch, h-row); 16 consecutive lanes = one batch. 65536 lanes =
// 1024 waves = 1 wave/SIMD device-wide (hard parallelism cap) -> pure
// single-wave latency optimization.
//
// R2 changes vs R1 (measured 250 cyc/step, 121 busy):
//  * DPP operand moved to src0: fmaf(ROTF(g,N), wg[N], y) so the compiler
//    can fold v_mov_b32_dpp + v_fma -> v_fmac_f32_dpp (-15 instr/step).
//  * State is g = 1/(2^y + 1) instead of h = 1-2g ("g-trick"):
//    h = 1 - 2g  =>  sum_j W[i][j] h_j = sum_j W[i][j] - 2 sum_j W[i][j] g_j.
//    The lane-constant sum_j W[i][j] folds into the bias, -2 into the
//    weights -> the tail fma disappears from the serial critical path.
//  * xp fma seeds chain 0; it depends only on x, so it issues during the
//    previous step's exp/rcp latency shadow.

#define S2LE 2.8853900817779268f  // 2*log2(e)

#define ROTI(v, N) __builtin_amdgcn_mov_dpp((v), 0x120 + (N), 0xF, 0xF, 0)
#define ROTF(v, N) __int_as_float(__builtin_amdgcn_mov_dpp(__float_as_int(v), 0x120 + (N), 0xF, 0xF, 0))

__global__ __launch_bounds__(64) void rnn_kernel(
    const float* __restrict__ x,
    const float* __restrict__ W_ih,
    const float* __restrict__ W_hh,
    const float* __restrict__ b_ih,
    const float* __restrict__ b_hh,
    const float* __restrict__ W_fc,
    const float* __restrict__ b_fc,
    float* __restrict__ out)
{
    const int li = (int)(threadIdx.x & 15u);
    const int b  = (int)((blockIdx.x * 64u + threadIdx.x) >> 4);

    const float* __restrict__ row = W_hh + li * 16;

    // Row sum for the g-trick bias fold.
    float sw = 0.0f;
#pragma unroll
    for (int j = 0; j < 16; ++j) sw += row[j];

    // Self-calibrating weight permutation (matches whatever permutation
    // row_ror:N actually applies, verified correct in R1), scaled by
    // -2*S2LE for the g-formulation.
    float wg[16];
    wg[0] = -2.0f * S2LE * row[li];
#define LW(N) { int s_ = ROTI(li, N); wg[N] = -2.0f * S2LE * row[s_]; }
    LW(1) LW(2) LW(3) LW(4) LW(5) LW(6) LW(7) LW(8)
    LW(9) LW(10) LW(11) LW(12) LW(13) LW(14) LW(15)
#undef LW

    const float wih  = W_ih[li] * S2LE;
    const float bias = (b_ih[li] + b_hh[li] + sw) * S2LE;
    const float wfc  = W_fc[li];
    const float bfc  = b_fc[0];

    const float4* __restrict__ xv = (const float4*)(x + (size_t)b * 512);

    float g = 0.5f;          // represents h = 0
    float4 xc = xv[0];

    // One step. DPP rotations of g feed src0 of fmac-shaped fmas (foldable
    // to v_fmac_f32_dpp / v_mul_f32_dpp). 4 independent chains of depth 4.
#define STEP(XP) do { \
    float y0 = (XP); \
    y0 = fmaf(g,           wg[0],  y0); \
    y0 = fmaf(ROTF(g, 1),  wg[1],  y0); \
    y0 = fmaf(ROTF(g, 2),  wg[2],  y0); \
    y0 = fmaf(ROTF(g, 3),  wg[3],  y0); \
    float y1 =  ROTF(g, 4) * wg[4]; \
    y1 = fmaf(ROTF(g, 5),  wg[5],  y1); \
    y1 = fmaf(ROTF(g, 6),  wg[6],  y1); \
    y1 = fmaf(ROTF(g, 7),  wg[7],  y1); \
    float y2 =  ROTF(g, 8) * wg[8]; \
    y2 = fmaf(ROTF(g, 9),  wg[9],  y2); \
    y2 = fmaf(ROTF(g, 10), wg[10], y2); \
    y2 = fmaf(ROTF(g, 11), wg[11], y2); \
    float y3 =  ROTF(g, 12) * wg[12]; \
    y3 = fmaf(ROTF(g, 13), wg[13], y3); \
    y3 = fmaf(ROTF(g, 14), wg[14], y3); \
    y3 = fmaf(ROTF(g, 15), wg[15], y3); \
    float s_ = (y0 + y1) + (y2 + y3); \
    float e_ = __builtin_amdgcn_exp2f(s_); \
    g = __builtin_amdgcn_rcpf(e_ + 1.0f); \
} while (0)

#pragma unroll 1
    for (int c = 0; c < 128; ++c) {
        float4 xn = xv[(c + 1) & 127];  // prefetch next chunk (wraps safely)
        // xp fmas depend only on x -> issue in the latency shadow of the
        // previous step's exp/rcp tail.
        float xp0 = fmaf(xc.x, wih, bias);
        float xp1 = fmaf(xc.y, wih, bias);
        float xp2 = fmaf(xc.z, wih, bias);
        float xp3 = fmaf(xc.w, wih, bias);
        STEP(xp0);
        STEP(xp1);
        STEP(xp2);
        STEP(xp3);
        xc = xn;
    }
#undef STEP

    // out[b] = sum_i h_i * W_fc[0][i] + b_fc, with h = 1 - 2g.
    float p = fmaf(-2.0f * wfc, g, wfc);
    p += ROTF(p, 8);
    p += ROTF(p, 4);
    p += ROTF(p, 2);
    p += ROTF(p, 1);
    if (li == 0) out[b] = p + bfc;
}

extern "C" void kernel_launch(void* const* d_in, const int* in_sizes, int n_in,
                              void* d_out, int out_size, void* d_ws, size_t ws_size,
                              hipStream_t stream) {
    const float* x    = (const float*)d_in[0];
    const float* W_ih = (const float*)d_in[1];
    const float* W_hh = (const float*)d_in[2];
    const float* b_ih = (const float*)d_in[3];
    const float* b_hh = (const float*)d_in[4];
    const float* W_fc = (const float*)d_in[5];
    const float* b_fc = (const float*)d_in[6];
    float* out = (float*)d_out;

    rnn_kernel<<<1024, 64, 0, stream>>>(x, W_ih, W_hh, b_ih, b_hh, W_fc, b_fc, out);
}